// Round 13
// baseline (127.182 us; speedup 1.0000x reference)
//
#include <hip/hip_runtime.h>
#include <hip/hip_bf16.h>
#include <stdint.h>

typedef __bf16 bf16_t;
typedef __bf16 bf16x8 __attribute__((ext_vector_type(8)));
typedef __bf16 bf16x4 __attribute__((ext_vector_type(4)));
typedef float  f32x4  __attribute__((ext_vector_type(4)));
typedef float  f32x16 __attribute__((ext_vector_type(16)));

#define LOG2E 1.44269504088896340736f

// ---------------- helpers ----------------

__device__ __forceinline__ void glds16(const bf16_t* g, bf16_t* l) {
  __builtin_amdgcn_global_load_lds(
      (const __attribute__((address_space(1))) void*)(g),
      (__attribute__((address_space(3))) void*)(l), 16, 0, 0);
}

// XOR-swizzled LDS element index for 128B rows: byte ^= (row&7)<<4.
// Involution + bijective within each row => read(swzi) of write(swzi) is identity.
__device__ __forceinline__ int swzi(int row, int cbyte) {
  return row * 64 + ((cbyte ^ ((row & 7) << 4)) >> 1);
}

// ---------------- fused: transpose+cast 4x W f32 -> Wt[n][k] bf16 (z<4) + cast x (z==4)

__global__ __launch_bounds__(256) void prep_kernel(
    const float* __restrict__ W0, const float* __restrict__ W1,
    const float* __restrict__ W2, const float* __restrict__ W3,
    bf16_t* __restrict__ T0, bf16_t* __restrict__ T1,
    bf16_t* __restrict__ T2, bf16_t* __restrict__ T3,
    const float* __restrict__ x, bf16_t* __restrict__ xb) {
  int tid = threadIdx.x;
  if (blockIdx.z == 4) {
    int bid = blockIdx.y * 16 + blockIdx.x;
    int base = bid * 16384;
#pragma unroll 4
    for (int i = 0; i < 16; ++i) {
      int idx = base + (i * 256 + tid) * 4;
      float4 v = *reinterpret_cast<const float4*>(x + idx);
      bf16x4 o = { (bf16_t)v.x, (bf16_t)v.y, (bf16_t)v.z, (bf16_t)v.w };
      *reinterpret_cast<bf16x4*>(xb + idx) = o;
    }
    return;
  }
  const float* W = blockIdx.z == 0 ? W0 : blockIdx.z == 1 ? W1 : blockIdx.z == 2 ? W2 : W3;
  bf16_t*      T = blockIdx.z == 0 ? T0 : blockIdx.z == 1 ? T1 : blockIdx.z == 2 ? T2 : T3;
  __shared__ float tile[64][65];
  int k0 = blockIdx.y * 64, n0 = blockIdx.x * 64;
  int rr = tid >> 4, cc = (tid & 15) * 4;
#pragma unroll
  for (int p = 0; p < 4; ++p) {
    float4 v = *reinterpret_cast<const float4*>(W + (size_t)(k0 + p * 16 + rr) * 1024 + n0 + cc);
    tile[p * 16 + rr][cc + 0] = v.x; tile[p * 16 + rr][cc + 1] = v.y;
    tile[p * 16 + rr][cc + 2] = v.z; tile[p * 16 + rr][cc + 3] = v.w;
  }
  __syncthreads();
#pragma unroll
  for (int p = 0; p < 4; ++p) {
    bf16x4 o;
#pragma unroll
    for (int i2 = 0; i2 < 4; ++i2) o[i2] = (bf16_t)tile[cc + i2][p * 16 + rr];
    *reinterpret_cast<bf16x4*>(T + (size_t)(n0 + p * 16 + rr) * 1024 + k0 + cc) = o;
  }
}

// ---------------- shared GEMM main loop: C[128x128] over K=1024 ----------------

__device__ __forceinline__ void gemm_tile(const bf16_t* __restrict__ A,
                                          const bf16_t* __restrict__ Wt,
                                          int m0, int n0,
                                          bf16_t* Al, bf16_t* Bl,
                                          f32x4 acc[4][4]) {
  int tid = threadIdx.x;
  int w = tid >> 6, lane = tid & 63, g = lane >> 4, t = lane & 15;
  int wr = w >> 1, wc = w & 1;
#pragma unroll
  for (int m = 0; m < 4; ++m)
#pragma unroll
    for (int n = 0; n < 4; ++n) acc[m][n] = (f32x4){0.f, 0.f, 0.f, 0.f};

  for (int k0 = 0; k0 < 1024; k0 += 32) {
#pragma unroll
    for (int r2 = 0; r2 < 2; ++r2) {
      int cb = r2 * 256 + w * 64;
      int cidx = cb + lane;
      int row = cidx >> 2, cc = cidx & 3;
      glds16(A  + (size_t)(m0 + row) * 1024 + k0 + cc * 8, Al + (size_t)cb * 8);
      glds16(Wt + (size_t)(n0 + row) * 1024 + k0 + cc * 8, Bl + (size_t)cb * 8);
    }
    __syncthreads();
    bf16x8 af[4], bfv[4];
#pragma unroll
    for (int m = 0; m < 4; ++m)
      af[m] = *reinterpret_cast<const bf16x8*>(Al + (wr * 64 + m * 16 + t) * 32 + g * 8);
#pragma unroll
    for (int n = 0; n < 4; ++n)
      bfv[n] = *reinterpret_cast<const bf16x8*>(Bl + (wc * 64 + n * 16 + t) * 32 + g * 8);
#pragma unroll
    for (int m = 0; m < 4; ++m)
#pragma unroll
      for (int n = 0; n < 4; ++n)
        acc[m][n] = __builtin_amdgcn_mfma_f32_16x16x32_bf16(af[m], bfv[n], acc[m][n], 0, 0, 0);
    __syncthreads();
  }
}

// ---------------- QKV projection GEMM ----------------
// z=0: Q = (x@Wq + bq) * 0.125 * LOG2E -> bf16 ; z=1: K ; z=2: V transposed Vt[b][n][s]

__global__ __launch_bounds__(256) void gemm_qkv_kernel(
    const bf16_t* __restrict__ A,
    const bf16_t* __restrict__ wtq, const bf16_t* __restrict__ wtk, const bf16_t* __restrict__ wtv,
    const float* __restrict__ bq, const float* __restrict__ bk, const float* __restrict__ bv,
    bf16_t* __restrict__ Qo, bf16_t* __restrict__ Ko, bf16_t* __restrict__ Vt) {
  __shared__ bf16_t Al[128 * 32];
  __shared__ bf16_t Bl[128 * 32];
  int z = blockIdx.z;
  const bf16_t* Wt  = z == 0 ? wtq : z == 1 ? wtk : wtv;
  const float* bias = z == 0 ? bq  : z == 1 ? bk  : bv;
  int m0 = blockIdx.x * 128, n0 = blockIdx.y * 128;
  f32x4 acc[4][4];
  gemm_tile(A, Wt, m0, n0, Al, Bl, acc);

  int tid = threadIdx.x, w = tid >> 6, lane = tid & 63, g = lane >> 4, t = lane & 15;
  int wr = w >> 1, wc = w & 1;
#pragma unroll
  for (int n = 0; n < 4; ++n) {
    int col = n0 + wc * 64 + n * 16 + t;
    float bv_ = bias[col];
#pragma unroll
    for (int m = 0; m < 4; ++m) {
      int row0 = m0 + wr * 64 + m * 16 + g * 4;
      if (z == 2) {
        bf16x4 o;
#pragma unroll
        for (int r = 0; r < 4; ++r) o[r] = (bf16_t)(acc[m][n][r] + bv_);
        *reinterpret_cast<bf16x4*>(Vt + ((size_t)(row0 >> 11) << 21) + (size_t)col * 2048 +
                                   (row0 & 2047)) = o;
      } else {
        float sc = (z == 0) ? (0.125f * LOG2E) : 1.0f;
        bf16_t* O = (z == 0) ? Qo : Ko;
#pragma unroll
        for (int r = 0; r < 4; ++r)
          O[(size_t)(row0 + r) * 1024 + col] = (bf16_t)((acc[m][n][r] + bv_) * sc);
      }
    }
  }
}

// ---------------- output projection GEMM -> fp32 d_out ----------------

__global__ __launch_bounds__(256) void gemm_out_kernel(
    const bf16_t* __restrict__ A, const bf16_t* __restrict__ Wt,
    const float* __restrict__ bias, float* __restrict__ out) {
  __shared__ bf16_t Al[128 * 32];
  __shared__ bf16_t Bl[128 * 32];
  int m0 = blockIdx.x * 128, n0 = blockIdx.y * 128;
  f32x4 acc[4][4];
  gemm_tile(A, Wt, m0, n0, Al, Bl, acc);

  int tid = threadIdx.x, w = tid >> 6, lane = tid & 63, g = lane >> 4, t = lane & 15;
  int wr = w >> 1, wc = w & 1;
#pragma unroll
  for (int n = 0; n < 4; ++n) {
    int col = n0 + wc * 64 + n * 16 + t;
    float bv_ = bias[col];
#pragma unroll
    for (int m = 0; m < 4; ++m) {
      int row0 = m0 + wr * 64 + m * 16 + g * 4;
#pragma unroll
      for (int r = 0; r < 4; ++r)
        out[(size_t)(row0 + r) * 1024 + col] = acc[m][n][r] + bv_;
    }
  }
}

// ---------------- flash attention: 32x32 swapped-QK, 8 waves x 32 q, P via LDS ----
// grid (S/256, H, B); 512 threads. KV tiles of 64 keys; K/V staged via
// global_load_lds (pre-swizzled source, as verified in R12). Swapped QK^T:
// mfma_32x32x16(A=K_frag, B=Q_frag) -> S^T: D col = q = lane&31,
// D row = key = (r&3) + 8*(r>>2) + 4*(lane>>5)  [m74/m101 HW-verified layout].
// A/B operands use identical k-placement k = 8*(lane>>5)+e (positionally safe).
// Softmax fully lane-local except one __shfl_xor(32) per max/sum (verified op;
// NO permlane, NO cvt_pk asm). P -> swizzled LDS [q][key] -> B-operand reads.
// O^T accumulates with col = q = lane&31 -> rescale/normalize lane-local.

__global__ __launch_bounds__(512) void attn_kernel(
    const bf16_t* __restrict__ Q, const bf16_t* __restrict__ K,
    const bf16_t* __restrict__ Vt, bf16_t* __restrict__ Ao) {
  __shared__ bf16_t Kl[2][64 * 64];   // [key][feat] (source-swizzled image), dbuf
  __shared__ bf16_t Vl[2][64 * 64];   // [feat][key] (source-swizzled image), dbuf
  __shared__ bf16_t Pl[8][32 * 64];   // per-wave P [q 32][key 64] XOR-swizzled

  const int tid = threadIdx.x, w = tid >> 6, lane = tid & 63;
  const int q31 = lane & 31, hi = lane >> 5;
  const int qbase = blockIdx.x * 256, h = blockIdx.y, b = blockIdx.z;
  bf16_t* Plw = Pl[w];

  // Q fragments (B-operand): qf[kk] elem e = Q[qrow][16kk + 8hi + e]
  const int qrow = qbase + w * 32 + q31;
  const bf16_t* qp = Q + (size_t)(b * 2048 + qrow) * 1024 + h * 64;
  bf16x8 qf[4];
#pragma unroll
  for (int kk = 0; kk < 4; ++kk)
    qf[kk] = *reinterpret_cast<const bf16x8*>(qp + kk * 16 + hi * 8);

  f32x16 o[2] = {};
  float mq = -1e30f, lq = 0.f;

  const bf16_t* Kbase = K + (size_t)b * 2048 * 1024 + h * 64;
  const bf16_t* Vbase = Vt + ((size_t)b << 21) + (size_t)(h * 64) * 2048;

  // glds staging geometry (verified R12): wave w covers rows 8w..8w+7.
  const int srow = 8 * w + (lane >> 3);
  const int scol = ((lane & 7) ^ (lane >> 3)) * 8;   // pre-swizzled source col (elems)
  const int ldsoff = w * 512;                        // wave-uniform chunk base (elems)

#define STAGE(jt_, buf_)                                                          \
  {                                                                               \
    int jn_ = ((jt_) & 31) * 64;                                                  \
    glds16(Kbase + (size_t)(jn_ + srow) * 1024 + scol, Kl[buf_] + ldsoff);        \
    glds16(Vbase + (size_t)srow * 2048 + jn_ + scol, Vl[buf_] + ldsoff);          \
  }

  STAGE(0, 0)   // prologue: tile 0 -> buf 0 (completed by iter-0 barrier)

  for (int jt = 0; jt < 32; ++jt) {
    const int cur = jt & 1, nxt = cur ^ 1;
    __syncthreads();            // vmcnt(0)+barrier: buf[cur] staged & visible
    STAGE(jt + 1, nxt)          // async stage next tile while computing this one

    const bf16_t* Kc = Kl[cur];
    const bf16_t* Vc = Vl[cur];

    // ---- QK^T (swapped): sc[kb] = S^T over keys 32kb+row(r,hi), q = q31
    f32x16 sc[2] = {};
    __builtin_amdgcn_s_setprio(1);
#pragma unroll
    for (int kk = 0; kk < 4; ++kk)
#pragma unroll
      for (int kb = 0; kb < 2; ++kb) {
        bf16x8 kf = *reinterpret_cast<const bf16x8*>(
            Kc + swzi(32 * kb + q31, kk * 32 + hi * 16));
        sc[kb] = __builtin_amdgcn_mfma_f32_32x32x16_bf16(kf, qf[kk], sc[kb], 0, 0, 0);
      }
    __builtin_amdgcn_s_setprio(0);

    // ---- online softmax: lane owns q=q31; halves combined via shfl_xor(32)
    float pm = -1e30f;
#pragma unroll
    for (int kb = 0; kb < 2; ++kb)
#pragma unroll
      for (int r = 0; r < 16; ++r) pm = fmaxf(pm, sc[kb][r]);
    pm = fmaxf(pm, __shfl_xor(pm, 32, 64));

    // T13 defer-max (log2 domain, THR=8 -> P bounded by 256); rescale lane-local
    if (!__all(pm - mq <= 8.0f)) {
      float mn = fmaxf(mq, pm);
      float corr = __builtin_amdgcn_exp2f(mq - mn);
      mq = mn;
      lq *= corr;
#pragma unroll
      for (int fb = 0; fb < 2; ++fb)
#pragma unroll
        for (int r = 0; r < 16; ++r) o[fb][r] *= corr;
    }

    // P = exp2(s - m); row-sum; write P to LDS as [q][key] (8 x b64, swizzled)
    float rs = 0.f;
#pragma unroll
    for (int kb = 0; kb < 2; ++kb)
#pragma unroll
      for (int r = 0; r < 16; ++r) {
        float e = __builtin_amdgcn_exp2f(sc[kb][r] - mq);
        sc[kb][r] = e;
        rs += e;
      }
    rs += __shfl_xor(rs, 32, 64);
    lq += rs;
#pragma unroll
    for (int kb = 0; kb < 2; ++kb)
#pragma unroll
      for (int j = 0; j < 4; ++j) {
        bf16x4 pw;
#pragma unroll
        for (int i = 0; i < 4; ++i) pw[i] = (bf16_t)sc[kb][4 * j + i];
        // reg r=4j+i -> key = 32kb + i + 8j + 4hi  (m74 row mapping)
        *reinterpret_cast<bf16x4*>(Plw + swzi(q31, (32 * kb + 8 * j + 4 * hi) * 2)) = pw;
      }

    // ---- PV: o[fb] = O^T[f = fb*32 + row(r,hi)][q = q31]
    __builtin_amdgcn_s_setprio(1);
#pragma unroll
    for (int ks = 0; ks < 4; ++ks) {
      bf16x8 pf = *reinterpret_cast<const bf16x8*>(
          Plw + swzi(q31, (16 * ks + 8 * hi) * 2));
#pragma unroll
      for (int fb = 0; fb < 2; ++fb) {
        bf16x8 vf = *reinterpret_cast<const bf16x8*>(
            Vc + swzi(fb * 32 + q31, ks * 32 + hi * 16));
        o[fb] = __builtin_amdgcn_mfma_f32_32x32x16_bf16(vf, pf, o[fb], 0, 0, 0);
      }
    }
    __builtin_amdgcn_s_setprio(0);
  }
#undef STAGE

  // ---- epilogue: normalize (lane-local), store bf16 (8 x b64)
  float linv = 1.f / lq;
  bf16_t* op = Ao + (size_t)(b * 2048 + qrow) * 1024 + h * 64;
#pragma unroll
  for (int fb = 0; fb < 2; ++fb)
#pragma unroll
    for (int j = 0; j < 4; ++j) {
      bf16x4 ov;
#pragma unroll
      for (int i = 0; i < 4; ++i) ov[i] = (bf16_t)(o[fb][4 * j + i] * linv);
      // reg r=4j+i -> feature = fb*32 + i + 8j + 4hi
      *reinterpret_cast<bf16x4*>(op + fb * 32 + 8 * j + 4 * hi) = ov;
    }
}

// ---------------- launch ----------------

extern "C" void kernel_launch(void* const* d_in, const int* in_sizes, int n_in,
                              void* d_out, int out_size, void* d_ws, size_t ws_size,
                              hipStream_t stream) {
  const float* x  = (const float*)d_in[0];
  const float* Wq = (const float*)d_in[1];
  const float* bq = (const float*)d_in[2];
  const float* Wk = (const float*)d_in[3];
  const float* bk = (const float*)d_in[4];
  const float* Wv = (const float*)d_in[5];
  const float* bv = (const float*)d_in[6];
  const float* Wo = (const float*)d_in[7];
  const float* bo = (const float*)d_in[8];
  float* out = (float*)d_out;
  char* ws = (char*)d_ws;

  bf16_t* xb  = (bf16_t*)(ws);
  bf16_t* wqt = (bf16_t*)(ws + 8388608);
  bf16_t* wkt = (bf16_t*)(ws + 8388608 + 2097152);
  bf16_t* wvt = (bf16_t*)(ws + 8388608 + 2 * 2097152);
  bf16_t* wot = (bf16_t*)(ws + 8388608 + 3 * 2097152);
  bf16_t* Qs  = (bf16_t*)(ws + 16777216);
  bf16_t* Kb  = (bf16_t*)(ws + 16777216 + 8388608);
  bf16_t* Vt  = (bf16_t*)(ws + 16777216 + 2 * 8388608);
  bf16_t* Ao  = (bf16_t*)(ws + 16777216 + 3 * 8388608);

  prep_kernel<<<dim3(16, 16, 5), 256, 0, stream>>>(Wq, Wk, Wv, Wo, wqt, wkt, wvt, wot, x, xb);
  gemm_qkv_kernel<<<dim3(32, 8, 3), 256, 0, stream>>>(xb, wqt, wkt, wvt, bq, bk, bv, Qs, Kb, Vt);
  attn_kernel<<<dim3(8, 16, 2), 512, 0, stream>>>(Qs, Kb, Vt, Ao);
  gemm_out_kernel<<<dim3(32, 8), 256, 0, stream>>>(Ao, wot, bo, out);
}

// Round 14
// 119.851 us; speedup vs baseline: 1.0612x; 1.0612x over previous
//
#include <hip/hip_runtime.h>
#include <hip/hip_bf16.h>
#include <stdint.h>

typedef __bf16 bf16_t;
typedef __bf16 bf16x8 __attribute__((ext_vector_type(8)));
typedef __bf16 bf16x4 __attribute__((ext_vector_type(4)));
typedef float  f32x4  __attribute__((ext_vector_type(4)));

#define LOG2E 1.44269504088896340736f

// ---------------- helpers ----------------

__device__ __forceinline__ void glds16(const bf16_t* g, bf16_t* l) {
  __builtin_amdgcn_global_load_lds(
      (const __attribute__((address_space(1))) void*)(g),
      (__attribute__((address_space(3))) void*)(l), 16, 0, 0);
}

// XOR-swizzled LDS element index for 128B rows: byte ^= (row&7)<<4.
// Involution + bijective within each row => read(swzi) of write(swzi) is identity.
__device__ __forceinline__ int swzi(int row, int cbyte) {
  return row * 64 + ((cbyte ^ ((row & 7) << 4)) >> 1);
}

// ---------------- fused: transpose+cast 4x W f32 -> Wt[n][k] bf16 (z<4) + cast x (z==4)

__global__ __launch_bounds__(256) void prep_kernel(
    const float* __restrict__ W0, const float* __restrict__ W1,
    const float* __restrict__ W2, const float* __restrict__ W3,
    bf16_t* __restrict__ T0, bf16_t* __restrict__ T1,
    bf16_t* __restrict__ T2, bf16_t* __restrict__ T3,
    const float* __restrict__ x, bf16_t* __restrict__ xb) {
  int tid = threadIdx.x;
  if (blockIdx.z == 4) {
    // cast x: 4,194,304 elems over 256 blocks -> 16384/block -> 16 float4/thread
    int bid = blockIdx.y * 16 + blockIdx.x;
    int base = bid * 16384;
#pragma unroll 4
    for (int i = 0; i < 16; ++i) {
      int idx = base + (i * 256 + tid) * 4;
      float4 v = *reinterpret_cast<const float4*>(x + idx);
      bf16x4 o = { (bf16_t)v.x, (bf16_t)v.y, (bf16_t)v.z, (bf16_t)v.w };
      *reinterpret_cast<bf16x4*>(xb + idx) = o;
    }
    return;
  }
  const float* W = blockIdx.z == 0 ? W0 : blockIdx.z == 1 ? W1 : blockIdx.z == 2 ? W2 : W3;
  bf16_t*      T = blockIdx.z == 0 ? T0 : blockIdx.z == 1 ? T1 : blockIdx.z == 2 ? T2 : T3;
  __shared__ float tile[64][65];
  int k0 = blockIdx.y * 64, n0 = blockIdx.x * 64;
  int rr = tid >> 4, cc = (tid & 15) * 4;
#pragma unroll
  for (int p = 0; p < 4; ++p) {
    float4 v = *reinterpret_cast<const float4*>(W + (size_t)(k0 + p * 16 + rr) * 1024 + n0 + cc);
    tile[p * 16 + rr][cc + 0] = v.x; tile[p * 16 + rr][cc + 1] = v.y;
    tile[p * 16 + rr][cc + 2] = v.z; tile[p * 16 + rr][cc + 3] = v.w;
  }
  __syncthreads();
#pragma unroll
  for (int p = 0; p < 4; ++p) {
    bf16x4 o;
#pragma unroll
    for (int i2 = 0; i2 < 4; ++i2) o[i2] = (bf16_t)tile[cc + i2][p * 16 + rr];
    *reinterpret_cast<bf16x4*>(T + (size_t)(n0 + p * 16 + rr) * 1024 + k0 + cc) = o;
  }
}

// ---------------- shared GEMM main loop: C[128x128] over K=1024 -------------------
// T3-minimum 2-phase (guide §5.5): double-buffered LDS, ONE barrier per K-step.
// STAGE(buf^1, k+32) issued BEFORE ds_read/MFMA of buf -> next tile's HBM latency
// hides under current tile's compute. Race-free: buf[cur^1]'s last readers finished
// before the previous barrier; this STAGE's DMA drains at this step's barrier.

__device__ __forceinline__ void gemm_tile(const bf16_t* __restrict__ A,
                                          const bf16_t* __restrict__ Wt,
                                          int m0, int n0,
                                          bf16_t (&Al)[2][128 * 32],
                                          bf16_t (&Bl)[2][128 * 32],
                                          f32x4 acc[4][4]) {
  int tid = threadIdx.x;
  int w = tid >> 6, lane = tid & 63, g = lane >> 4, t = lane & 15;
  int wr = w >> 1, wc = w & 1;
#pragma unroll
  for (int m = 0; m < 4; ++m)
#pragma unroll
    for (int n = 0; n < 4; ++n) acc[m][n] = (f32x4){0.f, 0.f, 0.f, 0.f};

#define GQSTAGE(buf_, k0_)                                                        \
  _Pragma("unroll")                                                               \
  for (int r2 = 0; r2 < 2; ++r2) {                                                \
    int cb = r2 * 256 + w * 64;                                                   \
    int cidx = cb + lane;                                                         \
    int row = cidx >> 2, cc2 = cidx & 3;                                          \
    glds16(A  + (size_t)(m0 + row) * 1024 + (k0_) + cc2 * 8, Al[buf_] + cb * 8);  \
    glds16(Wt + (size_t)(n0 + row) * 1024 + (k0_) + cc2 * 8, Bl[buf_] + cb * 8);  \
  }

  GQSTAGE(0, 0)
  __syncthreads();          // vmcnt(0) drain: buf0 staged & visible
  int cur = 0;
  for (int k0 = 0; k0 < 1024; k0 += 32) {
    if (k0 < 992) GQSTAGE(cur ^ 1, k0 + 32)   // prefetch next tile (in flight)
    bf16x8 af[4], bfv[4];
#pragma unroll
    for (int m = 0; m < 4; ++m)
      af[m] = *reinterpret_cast<const bf16x8*>(Al[cur] + (wr * 64 + m * 16 + t) * 32 + g * 8);
#pragma unroll
    for (int n = 0; n < 4; ++n)
      bfv[n] = *reinterpret_cast<const bf16x8*>(Bl[cur] + (wc * 64 + n * 16 + t) * 32 + g * 8);
#pragma unroll
    for (int m = 0; m < 4; ++m)
#pragma unroll
      for (int n = 0; n < 4; ++n)
        acc[m][n] = __builtin_amdgcn_mfma_f32_16x16x32_bf16(af[m], bfv[n], acc[m][n], 0, 0, 0);
    __syncthreads();        // drains this step's reads AND the prefetch DMA
    cur ^= 1;
  }
#undef GQSTAGE
}

// ---------------- QKV projection GEMM ----------------
// z=0: Q = (x@Wq + bq) * 0.125 * LOG2E -> bf16 ; z=1: K ; z=2: V transposed Vt[b][n][s]

__global__ __launch_bounds__(256) void gemm_qkv_kernel(
    const bf16_t* __restrict__ A,
    const bf16_t* __restrict__ wtq, const bf16_t* __restrict__ wtk, const bf16_t* __restrict__ wtv,
    const float* __restrict__ bq, const float* __restrict__ bk, const float* __restrict__ bv,
    bf16_t* __restrict__ Qo, bf16_t* __restrict__ Ko, bf16_t* __restrict__ Vt) {
  __shared__ bf16_t Al[2][128 * 32];
  __shared__ bf16_t Bl[2][128 * 32];
  int z = blockIdx.z;
  const bf16_t* Wt  = z == 0 ? wtq : z == 1 ? wtk : wtv;
  const float* bias = z == 0 ? bq  : z == 1 ? bk  : bv;
  int m0 = blockIdx.x * 128, n0 = blockIdx.y * 128;
  f32x4 acc[4][4];
  gemm_tile(A, Wt, m0, n0, Al, Bl, acc);

  int tid = threadIdx.x, w = tid >> 6, lane = tid & 63, g = lane >> 4, t = lane & 15;
  int wr = w >> 1, wc = w & 1;
#pragma unroll
  for (int n = 0; n < 4; ++n) {
    int col = n0 + wc * 64 + n * 16 + t;
    float bv_ = bias[col];
#pragma unroll
    for (int m = 0; m < 4; ++m) {
      int row0 = m0 + wr * 64 + m * 16 + g * 4;
      if (z == 2) {
        bf16x4 o;
#pragma unroll
        for (int r = 0; r < 4; ++r) o[r] = (bf16_t)(acc[m][n][r] + bv_);
        *reinterpret_cast<bf16x4*>(Vt + ((size_t)(row0 >> 11) << 21) + (size_t)col * 2048 +
                                   (row0 & 2047)) = o;
      } else {
        float sc = (z == 0) ? (0.125f * LOG2E) : 1.0f;
        bf16_t* O = (z == 0) ? Qo : Ko;
#pragma unroll
        for (int r = 0; r < 4; ++r)
          O[(size_t)(row0 + r) * 1024 + col] = (bf16_t)((acc[m][n][r] + bv_) * sc);
      }
    }
  }
}

// ---------------- output projection GEMM -> fp32 d_out ----------------

__global__ __launch_bounds__(256) void gemm_out_kernel(
    const bf16_t* __restrict__ A, const bf16_t* __restrict__ Wt,
    const float* __restrict__ bias, float* __restrict__ out) {
  __shared__ bf16_t Al[2][128 * 32];
  __shared__ bf16_t Bl[2][128 * 32];
  int m0 = blockIdx.x * 128, n0 = blockIdx.y * 128;
  f32x4 acc[4][4];
  gemm_tile(A, Wt, m0, n0, Al, Bl, acc);

  int tid = threadIdx.x, w = tid >> 6, lane = tid & 63, g = lane >> 4, t = lane & 15;
  int wr = w >> 1, wc = w & 1;
#pragma unroll
  for (int n = 0; n < 4; ++n) {
    int col = n0 + wc * 64 + n * 16 + t;
    float bv_ = bias[col];
#pragma unroll
    for (int m = 0; m < 4; ++m) {
      int row0 = m0 + wr * 64 + m * 16 + g * 4;
#pragma unroll
      for (int r = 0; r < 4; ++r)
        out[(size_t)(row0 + r) * 1024 + col] = acc[m][n][r] + bv_;
    }
  }
}

// ---------------- flash attention: swapped-QK 16x16, 8 waves x 16 q, K/V dbuf ------
// (R7 verbatim -- best measured config: 59.2 us.) grid (S/128, H, B); 512 threads.
// KV tiles of 64 keys, double-buffered LDS, one barrier per tile.
// Q pre-scaled by 0.125*LOG2E. Swapped QK^T: mfma(K_frag, Q_frag) -> S^T:
// D col = q = t, D row = key = 4g+r.

__global__ __launch_bounds__(512) void attn_kernel(
    const bf16_t* __restrict__ Q, const bf16_t* __restrict__ K,
    const bf16_t* __restrict__ Vt, bf16_t* __restrict__ Ao) {
  __shared__ bf16_t Kl[2][64 * 64];   // [key][feat]   XOR-swizzled, double-buffered
  __shared__ bf16_t Vl[2][64 * 64];   // [feat][key]   XOR-swizzled, double-buffered
  __shared__ bf16_t Pl[8][16 * 64];   // per-wave P [qrow 16][key 64] XOR-swizzled

  const int tid = threadIdx.x, w = tid >> 6, lane = tid & 63;
  const int g = lane >> 4, t = lane & 15;
  const int qbase = blockIdx.x * 128, h = blockIdx.y, b = blockIdx.z;
  bf16_t* Plw = Pl[w];

  // Q fragment (B-operand, col-slot = t): qf[kk] = Q[qrow][32kk + 8g + e]
  const bf16_t* qp = Q + (size_t)(b * 2048 + qbase + w * 16 + t) * 1024 + h * 64;
  bf16x8 qf[2];
#pragma unroll
  for (int kk = 0; kk < 2; ++kk)
    qf[kk] = *reinterpret_cast<const bf16x8*>(qp + kk * 32 + g * 8);

  f32x4 o[4];
#pragma unroll
  for (int n = 0; n < 4; ++n) o[n] = (f32x4){0.f, 0.f, 0.f, 0.f};
  float mq = -1e30f, lq = 0.f;

  const bf16_t* Kbase = K + (size_t)b * 2048 * 1024 + h * 64;
  const bf16_t* Vbase = Vt + ((size_t)b << 21) + (size_t)(h * 64) * 2048;

  // staging: 512 threads x exactly 1 chunk of 16B per array (64 rows x 8 chunks)
  const int r0 = tid >> 3, p0 = tid & 7;
  const int wo0 = swzi(r0, p0 * 16);

  // prologue: tile 0 -> buf 0 (visible after iter-0 barrier); tile 1 -> regs
  {
    bf16x8 k0v = *reinterpret_cast<const bf16x8*>(Kbase + (size_t)r0 * 1024 + p0 * 8);
    bf16x8 v0v = *reinterpret_cast<const bf16x8*>(Vbase + (size_t)r0 * 2048 + p0 * 8);
    *reinterpret_cast<bf16x8*>(Kl[0] + wo0) = k0v;
    *reinterpret_cast<bf16x8*>(Vl[0] + wo0) = v0v;
  }
  bf16x8 kst = *reinterpret_cast<const bf16x8*>(Kbase + (size_t)(64 + r0) * 1024 + p0 * 8);
  bf16x8 vst = *reinterpret_cast<const bf16x8*>(Vbase + (size_t)r0 * 2048 + 64 + p0 * 8);

  for (int jt = 0; jt < 32; ++jt) {
    const int cur = jt & 1, nxt = cur ^ 1;
    __syncthreads();   // buf[cur] writes visible; all waves done reading buf[nxt] (iter jt-1)
    // write tile jt+1 into buf[nxt] (read next iteration, after its barrier)
    *reinterpret_cast<bf16x8*>(Kl[nxt] + wo0) = kst;
    *reinterpret_cast<bf16x8*>(Vl[nxt] + wo0) = vst;
    // T14: prefetch tile jt+2 into regs (wraps harmlessly at the tail)
    {
      int jn = ((jt + 2) & 31) * 64;
      kst = *reinterpret_cast<const bf16x8*>(Kbase + (size_t)(jn + r0) * 1024 + p0 * 8);
      vst = *reinterpret_cast<const bf16x8*>(Vbase + (size_t)r0 * 2048 + jn + p0 * 8);
    }
    const bf16_t* Kc = Kl[cur];
    const bf16_t* Vc = Vl[cur];

    // ---- QK^T (swapped): s[c][r] = S[key = 16c + 4g + r][q = t]
    f32x4 s[4];
#pragma unroll
    for (int c = 0; c < 4; ++c) s[c] = (f32x4){0.f, 0.f, 0.f, 0.f};
#pragma unroll
    for (int kk = 0; kk < 2; ++kk)
#pragma unroll
      for (int c = 0; c < 4; ++c) {
        bf16x8 kf = *reinterpret_cast<const bf16x8*>(Kc + swzi(16 * c + t, 64 * kk + 16 * g));
        s[c] = __builtin_amdgcn_mfma_f32_16x16x32_bf16(kf, qf[kk], s[c], 0, 0, 0);
      }

    // ---- online softmax (state in q=t space)
    float pm = -1e30f;
#pragma unroll
    for (int c = 0; c < 4; ++c) {
      float a0 = fmaxf(s[c][0], s[c][1]);
      float a1 = fmaxf(s[c][2], s[c][3]);
      pm = fmaxf(pm, fmaxf(a0, a1));
    }
    pm = fmaxf(pm, __shfl_xor(pm, 16, 64));
    pm = fmaxf(pm, __shfl_xor(pm, 32, 64));

    // T13 defer-max (log2 domain, THR=8 -> P bounded by 256)
    if (!__all(pm - mq <= 8.0f)) {
      float mn = fmaxf(mq, pm);
      float corr = __builtin_amdgcn_exp2f(mq - mn);
      mq = mn;
      lq *= corr;
      float cr[4];
#pragma unroll
      for (int r = 0; r < 4; ++r) cr[r] = __shfl(corr, 4 * g + r, 64);
#pragma unroll
      for (int n = 0; n < 4; ++n)
#pragma unroll
        for (int r = 0; r < 4; ++r) o[n][r] *= cr[r];
    }

    // P = exp2(s - m); row-sum; pack to bf16 and store to Pl (4 x b64 writes)
    float rs = 0.f;
#pragma unroll
    for (int c = 0; c < 4; ++c) {
      bf16x4 pw;
#pragma unroll
      for (int r = 0; r < 4; ++r) {
        float e = __builtin_amdgcn_exp2f(s[c][r] - mq);
        rs += e;
        pw[r] = (bf16_t)e;
      }
      *reinterpret_cast<bf16x4*>(Plw + swzi(t, 32 * c + 8 * g)) = pw;
    }
    rs += __shfl_xor(rs, 16, 64);
    rs += __shfl_xor(rs, 32, 64);
    lq += rs;

    // ---- PV: o[n] (+)= P[q][key] * V[key][f]
#pragma unroll
    for (int kk = 0; kk < 2; ++kk) {
      bf16x8 pa = *reinterpret_cast<const bf16x8*>(Plw + swzi(t, 64 * kk + 16 * g));
#pragma unroll
      for (int n = 0; n < 4; ++n) {
        bf16x8 vbn = *reinterpret_cast<const bf16x8*>(Vc + swzi(16 * n + t, 64 * kk + 16 * g));
        o[n] = __builtin_amdgcn_mfma_f32_16x16x32_bf16(pa, vbn, o[n], 0, 0, 0);
      }
    }
  }

  // ---- epilogue: normalize (transpose 1/l from q=t to q=4g+r), store bf16
  float linv = 1.f / lq;
  float lr[4];
#pragma unroll
  for (int r = 0; r < 4; ++r) lr[r] = __shfl(linv, 4 * g + r, 64);
  bf16_t* op = Ao + (size_t)(b * 2048 + qbase + w * 16) * 1024 + h * 64;
#pragma unroll
  for (int n = 0; n < 4; ++n)
#pragma unroll
    for (int r = 0; r < 4; ++r)
      op[(size_t)(4 * g + r) * 1024 + 16 * n + t] = (bf16_t)(o[n][r] * lr[r]);
}

// ---------------- launch ----------------

extern "C" void kernel_launch(void* const* d_in, const int* in_sizes, int n_in,
                              void* d_out, int out_size, void* d_ws, size_t ws_size,
                              hipStream_t stream) {
  const float* x  = (const float*)d_in[0];
  const float* Wq = (const float*)d_in[1];
  const float* bq = (const float*)d_in[2];
  const float* Wk = (const float*)d_in[3];
  const float* bk = (const float*)d_in[4];
  const float* Wv = (const float*)d_in[5];
  const float* bv = (const float*)d_in[6];
  const float* Wo = (const float*)d_in[7];
  const float* bo = (const float*)d_in[8];
  float* out = (float*)d_out;
  char* ws = (char*)d_ws;

  bf16_t* xb  = (bf16_t*)(ws);
  bf16_t* wqt = (bf16_t*)(ws + 8388608);
  bf16_t* wkt = (bf16_t*)(ws + 8388608 + 2097152);
  bf16_t* wvt = (bf16_t*)(ws + 8388608 + 2 * 2097152);
  bf16_t* wot = (bf16_t*)(ws + 8388608 + 3 * 2097152);
  bf16_t* Qs  = (bf16_t*)(ws + 16777216);
  bf16_t* Kb  = (bf16_t*)(ws + 16777216 + 8388608);
  bf16_t* Vt  = (bf16_t*)(ws + 16777216 + 2 * 8388608);
  bf16_t* Ao  = (bf16_t*)(ws + 16777216 + 3 * 8388608);

  prep_kernel<<<dim3(16, 16, 5), 256, 0, stream>>>(Wq, Wk, Wv, Wo, wqt, wkt, wvt, wot, x, xb);
  gemm_qkv_kernel<<<dim3(32, 8, 3), 256, 0, stream>>>(xb, wqt, wkt, wvt, bq, bk, bv, Qs, Kb, Vt);
  attn_kernel<<<dim3(16, 16, 2), 512, 0, stream>>>(Qs, Kb, Vt, Ao);
  gemm_out_kernel<<<dim3(32, 8), 256, 0, stream>>>(Ao, wot, bo, out);
}